// Round 2
// baseline (227.588 us; speedup 1.0000x reference)
//
#include <hip/hip_runtime.h>
#include <hip/hip_bf16.h>

// NARX RNN. Inputs fp32, compute bf16 MFMA 16x16x32, output fp32.
// SKEWED schedule (compute u(s) once per slice, advance all active chains)
// + launch_bounds(256,2): the ONLY change this round.
//   At (256,3) the unified VGPR/AGPR cap is ~170 regs; the steady-state live
//   set (wxhf 32 + whhf 32 + bhf4 16 + hpk 24-32 + x prefetch 16 + upk 8 +
//   ha 16 + addressing ~15 ~= 160-175) spilled ~8 regs -> ~29 MB/dispatch of
//   scratch WRITE + matching reads, sitting on the recurrence critical path
//   (WRITE_SIZE 33 MB vs 4.2 MB output; VGPR_Count pinned at 84+84acc).
//   (256,2) gives 256 regs/wave -> zero spill; the 4 independent chains per
//   wave provide the ILP that the lost third wave used to.
// Layout math (verified in prior rounds):
//   C/D layout: lane (col=lane&15, q=lane>>4) holds rows 16tn+4q+r. Packing
//   pairs in natural order + the pi(p)-permuted Wxh^T/Whh^T staging makes
//   the produced packed frags directly valid as the next step's B operand.
//   pi(p) = 32(p>>5) + 16((p>>2)&1) + 4((p>>3)&3) + (p&3).
// s_win (resident Win^T) stride 40; pad slots 16..31 zeroed so q>=2 frag
// reads hit exact zeros. tanh has 2*log2(e) folded into Wxh/Whh/bh.

#define NG    2048
#define NXF   16
#define HIDN  64
#define DLAG  4
#define TOUTN 508
#define GBLK  64    // g rows per block (4 waves x 16)
#define TTB   4     // outputs per block
#define NSLC  (DLAG + TTB - 1)   // 7 slices per block
#define STR   72    // staging stride (shorts)
#define SW    40    // resident Win^T stride (shorts), 80B = 16B-aligned rows
#define SCALE 2.8853900817779268f   // 2*log2(e)

typedef short  s16x8 __attribute__((ext_vector_type(8)));
typedef float  f32x4 __attribute__((ext_vector_type(4)));
typedef unsigned int u32x4 __attribute__((ext_vector_type(4)));

__device__ __forceinline__ unsigned short f2bf(float f) {  // RTNE (init only)
    unsigned int u = __float_as_uint(f);
    u += 0x7fffu + ((u >> 16) & 1u);
    return (unsigned short)(u >> 16);
}
__device__ __forceinline__ unsigned int pk2bf(float a, float b) {  // [lo=a, hi=b]
    union { __hip_bfloat162 h2; unsigned int u; } c;
    c.h2 = __float22bfloat162_rn(float2{a, b});
    return c.u;
}
__device__ __forceinline__ float tanh_pre(float a) {
    // a is already scaled by 2*log2(e) (folded into weights/bias)
    float e = exp2f(a);
    return fmaf(-2.0f, __builtin_amdgcn_rcpf(e + 1.0f), 1.0f);
}

__global__ __launch_bounds__(256, 2)
void narx_kernel(const float* __restrict__ x,
                 const float* __restrict__ Win,
                 const float* __restrict__ bin_g,
                 const float* __restrict__ Wxh,
                 const float* __restrict__ Whh,
                 const float* __restrict__ bh_g,
                 const float* __restrict__ Wout,
                 const float* __restrict__ bout_g,
                 float* __restrict__ out)
{
    __shared__ unsigned short s_stage[HIDN * STR];  // transient weight staging
    __shared__ unsigned short s_win[HIDN * SW];     // resident Win^T, pad zeroed

    const int tid   = threadIdx.x;
    const int lane  = tid & 63;
    const int lm    = lane & 15;
    const int q     = lane >> 4;
    const int G0    = blockIdx.x * GBLK;
    const int tt0   = blockIdx.y * TTB;
    const int wrow0 = (tid >> 6) * 16;
    const int myg   = G0 + wrow0 + lm;

    // zero the t<DLAG head of the output (poisoned before every launch)
    if (blockIdx.y == 0 && tid < GBLK) {
        #pragma unroll
        for (int t2 = 0; t2 < DLAG; ++t2)
            out[t2 * NG + G0 + tid] = 0.0f;
    }

    // zero s_win pad slots 16..31 (disjoint from data slots 0..15: no race;
    // slots 32..39 are never read)
    {
        int r = tid >> 2, c0 = 16 + (tid & 3) * 4;
        #pragma unroll
        for (int i = 0; i < 4; ++i) s_win[r * SW + c0 + i] = 0;
    }

    // ---- stage Wxh^T / Whh^T with K permuted by pi, scaled; frags to regs ----
    const int p0  = tid >> 2;              // K-position this thread stages
    const int pi0 = 32*(p0>>5) + 16*((p0>>2)&1) + 4*((p0>>3)&3) + (p0&3);
    const int n0  = (tid & 3) * 16;

    s16x8 wxhf[4][2], whhf[4][2];
    {
        const float* src = Wxh + pi0 * HIDN + n0;
        #pragma unroll
        for (int i = 0; i < 16; ++i)
            s_stage[(n0 + i) * STR + p0] = f2bf(src[i] * SCALE);
    }
    __syncthreads();
    #pragma unroll
    for (int tn = 0; tn < 4; ++tn)
        #pragma unroll
        for (int kk = 0; kk < 2; ++kk)
            wxhf[tn][kk] = *(const s16x8*)&s_stage[(tn*16 + lm) * STR + kk*32 + q*8];
    __syncthreads();
    {
        const float* src = Whh + pi0 * HIDN + n0;
        #pragma unroll
        for (int i = 0; i < 16; ++i)
            s_stage[(n0 + i) * STR + p0] = f2bf(src[i] * SCALE);
    }
    __syncthreads();   // staging writes are cross-wave: must fence
    #pragma unroll
    for (int tn = 0; tn < 4; ++tn)
        #pragma unroll
        for (int kk = 0; kk < 2; ++kk)
            whhf[tn][kk] = *(const s16x8*)&s_stage[(tn*16 + lm) * STR + kk*32 + q*8];

    // ---- resident Win^T (unpermuted K = x features), slots k<16 ----
    {
        int k = tid >> 4, nn = (tid & 15) * 4;
        const float* src = Win + k * HIDN + nn;
        #pragma unroll
        for (int i = 0; i < 4; ++i) s_win[(nn + i) * SW + k] = f2bf(src[i]);
    }

    // b_h (scaled) fp32 per-lane: unit n = tn*16 + q*4 + r
    f32x4 bhf4[4];
    #pragma unroll
    for (int tn = 0; tn < 4; ++tn) {
        f32x4 h4 = *(const f32x4*)&bh_g[tn*16 + q*4];
        bhf4[tn] = h4 * SCALE;
    }
    const float boutf = bout_g[0];
    __syncthreads();   // s_win fully written; staging dead

    // ---- skewed hot loop over slices tt0 .. tt0+6 ----
    const size_t slcstride = (size_t)NG * NXF;
    const float* px = x + ((size_t)tt0 * NG + myg) * NXF + q * 8;

    f32x4 xa = {0,0,0,0}, xb = {0,0,0,0};   // current slice (raw f32, q<2)
    f32x4 na = {0,0,0,0}, nb = {0,0,0,0};   // prefetched next slice
    if (q < 2) {
        xa = *(const f32x4*)px;
        xb = *(const f32x4*)(px + 4);
    }

    u32x4 hpk[TTB][2];   // packed h per output chain (= next step's B-frags)

    #pragma unroll
    for (int s = 0; s < NSLC; ++s) {
        // prefetch slice s+1 (independent; lands during this slice's compute)
        if (q < 2 && s + 1 < NSLC) {
            const float* pn = px + (size_t)(s + 1) * slcstride;
            na = *(const f32x4*)pn;
            nb = *(const f32x4*)(pn + 4);
        }

        // ---- u(s) = relu(x_s @ Win + bin), computed once, packed bf16 ----
        s16x8 xf = {0,0,0,0,0,0,0,0};
        if (q < 2) {   // features k = q*8+j < 16; lanes q>=2 supply zeros
            u32x4 xi;
            xi[0] = pk2bf(xa[0], xa[1]);
            xi[1] = pk2bf(xa[2], xa[3]);
            xi[2] = pk2bf(xb[0], xb[1]);
            xi[3] = pk2bf(xb[2], xb[3]);
            xf = __builtin_bit_cast(s16x8, xi);
        }
        u32x4 upk[2];
        #pragma unroll
        for (int tj = 0; tj < 4; ++tj) {
            s16x8 wf = *(const s16x8*)&s_win[(tj*16 + lm) * SW + q*8];
            f32x4 c  = *(const f32x4*)&bin_g[tj*16 + q*4];
            f32x4 ua = __builtin_amdgcn_mfma_f32_16x16x32_bf16(wf, xf, c, 0, 0, 0);
            upk[tj>>1][(tj&1)*2+0] = pk2bf(fmaxf(ua[0],0.f), fmaxf(ua[1],0.f));
            upk[tj>>1][(tj&1)*2+1] = pk2bf(fmaxf(ua[2],0.f), fmaxf(ua[3],0.f));
        }
        const s16x8 uf0 = __builtin_bit_cast(s16x8, upk[0]);
        const s16x8 uf1 = __builtin_bit_cast(s16x8, upk[1]);

        // ---- advance every active chain: ti in [s-3, s] (independent!) ----
        #pragma unroll
        for (int ti = 0; ti < TTB; ++ti) {
            if (ti > s || ti < s - (DLAG - 1)) continue;   // compile-time pruned

            f32x4 ha[4];
            #pragma unroll
            for (int tn = 0; tn < 4; ++tn)
                ha[tn] = __builtin_amdgcn_mfma_f32_16x16x32_bf16(
                    wxhf[tn][0], uf0, bhf4[tn], 0, 0, 0);
            #pragma unroll
            for (int tn = 0; tn < 4; ++tn)
                ha[tn] = __builtin_amdgcn_mfma_f32_16x16x32_bf16(
                    wxhf[tn][1], uf1, ha[tn], 0, 0, 0);

            if (ti != s) {   // d>0: previous h exists
                #pragma unroll
                for (int kk = 0; kk < 2; ++kk) {
                    s16x8 hf = __builtin_bit_cast(s16x8, hpk[ti][kk]);
                    #pragma unroll
                    for (int tn = 0; tn < 4; ++tn)
                        ha[tn] = __builtin_amdgcn_mfma_f32_16x16x32_bf16(
                            whhf[tn][kk], hf, ha[tn], 0, 0, 0);
                }
            }

            if (ti > s - (DLAG - 1)) {
                // not the last step of this chain: h = tanh(.), pack for reuse
                #pragma unroll
                for (int tn = 0; tn < 4; ++tn) {
                    hpk[ti][tn>>1][(tn&1)*2+0] =
                        pk2bf(tanh_pre(ha[tn][0]), tanh_pre(ha[tn][1]));
                    hpk[ti][tn>>1][(tn&1)*2+1] =
                        pk2bf(tanh_pre(ha[tn][2]), tanh_pre(ha[tn][3]));
                }
            } else {
                // last step (s == ti+3): y = Wout.h + bout
                float acc = 0.f;
                #pragma unroll
                for (int tn = 0; tn < 4; ++tn) {
                    f32x4 wo = *(const f32x4*)&Wout[tn*16 + q*4];
                    #pragma unroll
                    for (int r = 0; r < 4; ++r)
                        acc += tanh_pre(ha[tn][r]) * wo[r];
                }
                acc += __shfl_xor(acc, 16, 64);
                acc += __shfl_xor(acc, 32, 64);
                if (lane < 16)
                    out[(size_t)(tt0 + ti + DLAG) * NG + G0 + wrow0 + lane] =
                        acc + boutf;
            }
        }

        xa = na;
        xb = nb;
    }
}

extern "C" void kernel_launch(void* const* d_in, const int* in_sizes, int n_in,
                              void* d_out, int out_size, void* d_ws, size_t ws_size,
                              hipStream_t stream) {
    const float* x    = (const float*)d_in[0];
    const float* Win  = (const float*)d_in[1];
    const float* bin  = (const float*)d_in[2];
    const float* Wxh  = (const float*)d_in[3];
    const float* Whh  = (const float*)d_in[4];
    const float* bh   = (const float*)d_in[5];
    const float* Wout = (const float*)d_in[6];
    const float* bout = (const float*)d_in[7];
    float* out = (float*)d_out;

    dim3 grid(NG / GBLK, TOUTN / TTB);  // (32, 127)
    narx_kernel<<<grid, dim3(256), 0, stream>>>(x, Win, bin, Wxh, Whh, bh, Wout, bout, out);
}

// Round 3
// 217.017 us; speedup vs baseline: 1.0487x; 1.0487x over previous
//
#include <hip/hip_runtime.h>
#include <hip/hip_bf16.h>

// NARX RNN. Inputs fp32, compute bf16 MFMA 16x16x32, output fp32.
// SKEWED schedule (compute u(s) once per slice, advance all active chains).
// This round: back to launch_bounds(256,3) (3 waves/SIMD was worth ~17us in
// R1) with the register overshoot removed so there are NO spills:
//   R1 (256,3): spills (WRITE 33MB), 174us. R2 (256,2): no spills, 191us.
//   VALU-busy time identical (113 vs 114us) -> latency-bound; want 3 waves
//   AND spill-free. Unified demand was ~190 vs the 170 cap; shaved ~32:
//   1) bin folded into the u-MFMA K dimension: x-frag uses only k<16 of
//      K=32; bin (bf16) staged into s_win k-slot 16, q==2 lanes supply
//      bf16(1.0) at element 0 -> pre = x@Win + 1*bin, C = inline zero.
//      Kills 16 hoisted bin regs + 4 global loads/slice.
//   2) x kept only as packed bf16 (xf_cur/xf_nxt, 8 regs vs 16 fp32).
// Layout math (verified in prior rounds):
//   C/D layout: lane (col=lane&15, q=lane>>4) holds rows 16tn+4q+r. Packing
//   pairs in natural order + the pi(p)-permuted Wxh^T/Whh^T staging makes
//   the produced packed frags directly valid as the next step's B operand.
//   pi(p) = 32(p>>5) + 16((p>>2)&1) + 4((p>>3)&3) + (p&3).
//   A/B share the common k-map (element e of lane-group q <-> k = q*8+e),
//   so the bin row at k=16 pairs A(q=2,e=0) with B(q=2,e=0) consistently.
// s_win (resident Win^T) stride 40; pad slots 17..31 zeroed so unused frag
// reads hit exact zeros. tanh has 2*log2(e) folded into Wxh/Whh/bh.

#define NG    2048
#define NXF   16
#define HIDN  64
#define DLAG  4
#define TOUTN 508
#define GBLK  64    // g rows per block (4 waves x 16)
#define TTB   4     // outputs per block
#define NSLC  (DLAG + TTB - 1)   // 7 slices per block
#define STR   72    // staging stride (shorts)
#define SW    40    // resident Win^T stride (shorts), 80B = 16B-aligned rows
#define SCALE 2.8853900817779268f   // 2*log2(e)

typedef short  s16x8 __attribute__((ext_vector_type(8)));
typedef float  f32x4 __attribute__((ext_vector_type(4)));
typedef unsigned int u32x4 __attribute__((ext_vector_type(4)));

__device__ __forceinline__ unsigned short f2bf(float f) {  // RTNE (init only)
    unsigned int u = __float_as_uint(f);
    u += 0x7fffu + ((u >> 16) & 1u);
    return (unsigned short)(u >> 16);
}
__device__ __forceinline__ unsigned int pk2bf(float a, float b) {  // [lo=a, hi=b]
    union { __hip_bfloat162 h2; unsigned int u; } c;
    c.h2 = __float22bfloat162_rn(float2{a, b});
    return c.u;
}
__device__ __forceinline__ float tanh_pre(float a) {
    // a is already scaled by 2*log2(e) (folded into weights/bias)
    float e = exp2f(a);
    return fmaf(-2.0f, __builtin_amdgcn_rcpf(e + 1.0f), 1.0f);
}

__global__ __launch_bounds__(256, 3)
void narx_kernel(const float* __restrict__ x,
                 const float* __restrict__ Win,
                 const float* __restrict__ bin_g,
                 const float* __restrict__ Wxh,
                 const float* __restrict__ Whh,
                 const float* __restrict__ bh_g,
                 const float* __restrict__ Wout,
                 const float* __restrict__ bout_g,
                 float* __restrict__ out)
{
    __shared__ unsigned short s_stage[HIDN * STR];  // transient weight staging
    __shared__ unsigned short s_win[HIDN * SW];     // resident Win^T + bin row

    const int tid   = threadIdx.x;
    const int lane  = tid & 63;
    const int lm    = lane & 15;
    const int q     = lane >> 4;
    const int G0    = blockIdx.x * GBLK;
    const int tt0   = blockIdx.y * TTB;
    const int wrow0 = (tid >> 6) * 16;
    const int myg   = G0 + wrow0 + lm;

    // zero the t<DLAG head of the output (poisoned before every launch)
    if (blockIdx.y == 0 && tid < GBLK) {
        #pragma unroll
        for (int t2 = 0; t2 < DLAG; ++t2)
            out[t2 * NG + G0 + tid] = 0.0f;
    }

    // s_win slots 16..31: slot 16 = bin (bf16, the bias-in-K row), 17..31 = 0
    // (disjoint from data slots 0..15: no race; slots 32..39 never read)
    {
        int r = tid >> 2, c0 = 16 + (tid & 3) * 4;
        #pragma unroll
        for (int i = 0; i < 4; ++i) {
            unsigned short v = 0;
            if (c0 + i == 16) v = f2bf(bin_g[r]);
            s_win[r * SW + c0 + i] = v;
        }
    }

    // ---- stage Wxh^T / Whh^T with K permuted by pi, scaled; frags to regs ----
    const int p0  = tid >> 2;              // K-position this thread stages
    const int pi0 = 32*(p0>>5) + 16*((p0>>2)&1) + 4*((p0>>3)&3) + (p0&3);
    const int n0  = (tid & 3) * 16;

    s16x8 wxhf[4][2], whhf[4][2];
    {
        const float* src = Wxh + pi0 * HIDN + n0;
        #pragma unroll
        for (int i = 0; i < 16; ++i)
            s_stage[(n0 + i) * STR + p0] = f2bf(src[i] * SCALE);
    }
    __syncthreads();
    #pragma unroll
    for (int tn = 0; tn < 4; ++tn)
        #pragma unroll
        for (int kk = 0; kk < 2; ++kk)
            wxhf[tn][kk] = *(const s16x8*)&s_stage[(tn*16 + lm) * STR + kk*32 + q*8];
    __syncthreads();
    {
        const float* src = Whh + pi0 * HIDN + n0;
        #pragma unroll
        for (int i = 0; i < 16; ++i)
            s_stage[(n0 + i) * STR + p0] = f2bf(src[i] * SCALE);
    }
    __syncthreads();   // staging writes are cross-wave: must fence
    #pragma unroll
    for (int tn = 0; tn < 4; ++tn)
        #pragma unroll
        for (int kk = 0; kk < 2; ++kk)
            whhf[tn][kk] = *(const s16x8*)&s_stage[(tn*16 + lm) * STR + kk*32 + q*8];

    // ---- resident Win^T (unpermuted K = x features), slots k<16 ----
    {
        int k = tid >> 4, nn = (tid & 15) * 4;
        const float* src = Win + k * HIDN + nn;
        #pragma unroll
        for (int i = 0; i < 4; ++i) s_win[(nn + i) * SW + k] = f2bf(src[i]);
    }

    // b_h (scaled) fp32 per-lane: unit n = tn*16 + q*4 + r
    f32x4 bhf4[4];
    #pragma unroll
    for (int tn = 0; tn < 4; ++tn) {
        f32x4 h4 = *(const f32x4*)&bh_g[tn*16 + q*4];
        bhf4[tn] = h4 * SCALE;
    }
    const float boutf = bout_g[0];
    __syncthreads();   // s_win fully written; staging dead

    // ---- skewed hot loop over slices tt0 .. tt0+6 ----
    const size_t slcstride = (size_t)NG * NXF;
    const float* px = x + ((size_t)tt0 * NG + myg) * NXF + q * 8;

    // load + pack slice s into a ready B-frag (q==2 carries the bias 1.0)
    auto load_pack = [&](int s) -> s16x8 {
        s16x8 r = {0,0,0,0,0,0,0,0};
        if (q == 2) r[0] = (short)0x3F80;   // bf16(1.0) at k=16 -> +bin
        if (q < 2) {   // features k = q*8+j < 16
            const float* p = px + (size_t)s * slcstride;
            f32x4 a = *(const f32x4*)p;
            f32x4 b = *(const f32x4*)(p + 4);
            u32x4 xi;
            xi[0] = pk2bf(a[0], a[1]);
            xi[1] = pk2bf(a[2], a[3]);
            xi[2] = pk2bf(b[0], b[1]);
            xi[3] = pk2bf(b[2], b[3]);
            r = __builtin_bit_cast(s16x8, xi);
        }
        return r;
    };

    u32x4 hpk[TTB][2];   // packed h per output chain (= next step's B-frags)
    s16x8 xf = load_pack(0);

    #pragma unroll
    for (int s = 0; s < NSLC; ++s) {
        // prefetch+pack slice s+1 (independent; lands during this compute)
        s16x8 xf_nxt = xf;
        if (s + 1 < NSLC) xf_nxt = load_pack(s + 1);

        // ---- u(s) = relu(x_s @ Win + bin), computed once, packed bf16 ----
        u32x4 upk[2];
        #pragma unroll
        for (int tj = 0; tj < 4; ++tj) {
            s16x8 wf = *(const s16x8*)&s_win[(tj*16 + lm) * SW + q*8];
            f32x4 zc = {0.f, 0.f, 0.f, 0.f};
            f32x4 ua = __builtin_amdgcn_mfma_f32_16x16x32_bf16(wf, xf, zc, 0, 0, 0);
            upk[tj>>1][(tj&1)*2+0] = pk2bf(fmaxf(ua[0],0.f), fmaxf(ua[1],0.f));
            upk[tj>>1][(tj&1)*2+1] = pk2bf(fmaxf(ua[2],0.f), fmaxf(ua[3],0.f));
        }
        const s16x8 uf0 = __builtin_bit_cast(s16x8, upk[0]);
        const s16x8 uf1 = __builtin_bit_cast(s16x8, upk[1]);

        // ---- advance every active chain: ti in [s-3, s] (independent!) ----
        #pragma unroll
        for (int ti = 0; ti < TTB; ++ti) {
            if (ti > s || ti < s - (DLAG - 1)) continue;   // compile-time pruned

            f32x4 ha[4];
            #pragma unroll
            for (int tn = 0; tn < 4; ++tn)
                ha[tn] = __builtin_amdgcn_mfma_f32_16x16x32_bf16(
                    wxhf[tn][0], uf0, bhf4[tn], 0, 0, 0);
            #pragma unroll
            for (int tn = 0; tn < 4; ++tn)
                ha[tn] = __builtin_amdgcn_mfma_f32_16x16x32_bf16(
                    wxhf[tn][1], uf1, ha[tn], 0, 0, 0);

            if (ti != s) {   // d>0: previous h exists
                #pragma unroll
                for (int kk = 0; kk < 2; ++kk) {
                    s16x8 hf = __builtin_bit_cast(s16x8, hpk[ti][kk]);
                    #pragma unroll
                    for (int tn = 0; tn < 4; ++tn)
                        ha[tn] = __builtin_amdgcn_mfma_f32_16x16x32_bf16(
                            whhf[tn][kk], hf, ha[tn], 0, 0, 0);
                }
            }

            if (ti > s - (DLAG - 1)) {
                // not the last step of this chain: h = tanh(.), pack for reuse
                #pragma unroll
                for (int tn = 0; tn < 4; ++tn) {
                    hpk[ti][tn>>1][(tn&1)*2+0] =
                        pk2bf(tanh_pre(ha[tn][0]), tanh_pre(ha[tn][1]));
                    hpk[ti][tn>>1][(tn&1)*2+1] =
                        pk2bf(tanh_pre(ha[tn][2]), tanh_pre(ha[tn][3]));
                }
            } else {
                // last step (s == ti+3): y = Wout.h + bout (tv kept in f32)
                float acc = 0.f;
                #pragma unroll
                for (int tn = 0; tn < 4; ++tn) {
                    f32x4 wo = *(const f32x4*)&Wout[tn*16 + q*4];
                    #pragma unroll
                    for (int r = 0; r < 4; ++r)
                        acc += tanh_pre(ha[tn][r]) * wo[r];
                }
                acc += __shfl_xor(acc, 16, 64);
                acc += __shfl_xor(acc, 32, 64);
                if (lane < 16)
                    out[(size_t)(tt0 + ti + DLAG) * NG + G0 + wrow0 + lane] =
                        acc + boutf;
            }
        }

        xf = xf_nxt;
    }
}

extern "C" void kernel_launch(void* const* d_in, const int* in_sizes, int n_in,
                              void* d_out, int out_size, void* d_ws, size_t ws_size,
                              hipStream_t stream) {
    const float* x    = (const float*)d_in[0];
    const float* Win  = (const float*)d_in[1];
    const float* bin  = (const float*)d_in[2];
    const float* Wxh  = (const float*)d_in[3];
    const float* Whh  = (const float*)d_in[4];
    const float* bh   = (const float*)d_in[5];
    const float* Wout = (const float*)d_in[6];
    const float* bout = (const float*)d_in[7];
    float* out = (float*)d_out;

    dim3 grid(NG / GBLK, TOUTN / TTB);  // (32, 127)
    narx_kernel<<<grid, dim3(256), 0, stream>>>(x, Win, bin, Wxh, Whh, bh, Wout, bout, out);
}

// Round 4
// 205.705 us; speedup vs baseline: 1.1064x; 1.0550x over previous
//
#include <hip/hip_runtime.h>
#include <hip/hip_bf16.h>

// NARX RNN. Inputs fp32, compute bf16 MFMA 16x16x32, output fp32.
// SKEWED schedule (compute u(s) once per slice, advance all active chains),
// launch_bounds(256,3), spill-free (R3 verified: WRITE_SIZE = output only).
// This round (R4):
//  1) Weight-fragment packing moved to a one-block SETUP kernel writing
//     d_ws: all 4064 main blocks were re-staging identical Wxh/Whh frags
//     through LDS (32 scalar loads + f2bf + conflicted 2B writes + b128
//     reads + 3 barriers each). SQ_LDS_BANK_CONFLICT ~7.0M was invariant
//     to s_win stride changes -> conflicts live in that staging phase.
//     Main kernel now loads 16 coalesced dwordx4 frags from ws (L2-hit).
//  2) tanh exp2: raw v_exp_f32 (builtin / asm fallback) instead of ocml
//     exp2f; inputs are pre-scaled, large-negative underflows gracefully
//     to tanh=-1. Cuts the OCML guard instructions x256 calls/wave.
// Layout math (verified R0-R3):
//   C/D layout: lane (col=lane&15, q=lane>>4) holds rows 16tn+4q+r. Packing
//   pairs in natural order + the pi(p)-permuted Wxh^T/Whh^T staging makes
//   the produced packed frags directly valid as the next step's B operand.
//   pi(p) = 32(p>>5) + 16((p>>2)&1) + 4((p>>3)&3) + (p&3).
//   bin folded into u-MFMA K slot 16 (q==2 lanes carry bf16(1.0)).
// s_win stride 40; pad slots 17..31 zeroed. 2*log2(e) folded into weights.

#define NG    2048
#define NXF   16
#define HIDN  64
#define DLAG  4
#define TOUTN 508
#define GBLK  64    // g rows per block (4 waves x 16)
#define TTB   4     // outputs per block
#define NSLC  (DLAG + TTB - 1)   // 7 slices per block
#define STR   72    // setup-kernel staging stride (shorts)
#define SW    40    // resident Win^T stride (shorts), 80B = 16B-aligned rows
#define SCALE 2.8853900817779268f   // 2*log2(e)
#define WXH_OFF 0       // ws offsets in shorts
#define WHH_OFF 4096

typedef short  s16x8 __attribute__((ext_vector_type(8)));
typedef float  f32x4 __attribute__((ext_vector_type(4)));
typedef unsigned int u32x4 __attribute__((ext_vector_type(4)));

__device__ __forceinline__ unsigned short f2bf(float f) {  // RTNE (init only)
    unsigned int u = __float_as_uint(f);
    u += 0x7fffu + ((u >> 16) & 1u);
    return (unsigned short)(u >> 16);
}
__device__ __forceinline__ unsigned int pk2bf(float a, float b) {  // [lo=a, hi=b]
    union { __hip_bfloat162 h2; unsigned int u; } c;
    c.h2 = __float22bfloat162_rn(float2{a, b});
    return c.u;
}
__device__ __forceinline__ float raw_exp2(float a) {
#if __has_builtin(__builtin_amdgcn_exp2f)
    return __builtin_amdgcn_exp2f(a);
#else
    float r;
    asm("v_exp_f32 %0, %1" : "=v"(r) : "v"(a));
    return r;
#endif
}
__device__ __forceinline__ float tanh_pre(float a) {
    // a is already scaled by 2*log2(e) (folded into weights/bias)
    float e = raw_exp2(a);
    return fmaf(-2.0f, __builtin_amdgcn_rcpf(e + 1.0f), 1.0f);
}

// ---- setup: pack Wxh/Whh MFMA fragments (pi-permuted, scaled) into ws ----
__global__ __launch_bounds__(256, 1)
void pack_weights(const float* __restrict__ Wxh,
                  const float* __restrict__ Whh,
                  unsigned short* __restrict__ ws)
{
    __shared__ unsigned short s_stage[HIDN * STR];
    const int tid  = threadIdx.x;
    const int lane = tid & 63;
    const int lm   = lane & 15;
    const int q    = lane >> 4;
    const int p0   = tid >> 2;
    const int pi0  = 32*(p0>>5) + 16*((p0>>2)&1) + 4*((p0>>3)&3) + (p0&3);
    const int n0   = (tid & 3) * 16;

    {
        const float* src = Wxh + pi0 * HIDN + n0;
        #pragma unroll
        for (int i = 0; i < 16; ++i)
            s_stage[(n0 + i) * STR + p0] = f2bf(src[i] * SCALE);
    }
    __syncthreads();
    if (tid < 64) {
        #pragma unroll
        for (int tn = 0; tn < 4; ++tn)
            #pragma unroll
            for (int kk = 0; kk < 2; ++kk)
                *(s16x8*)&ws[WXH_OFF + lane*64 + tn*16 + kk*8] =
                    *(const s16x8*)&s_stage[(tn*16 + lm) * STR + kk*32 + q*8];
    }
    __syncthreads();
    {
        const float* src = Whh + pi0 * HIDN + n0;
        #pragma unroll
        for (int i = 0; i < 16; ++i)
            s_stage[(n0 + i) * STR + p0] = f2bf(src[i] * SCALE);
    }
    __syncthreads();
    if (tid < 64) {
        #pragma unroll
        for (int tn = 0; tn < 4; ++tn)
            #pragma unroll
            for (int kk = 0; kk < 2; ++kk)
                *(s16x8*)&ws[WHH_OFF + lane*64 + tn*16 + kk*8] =
                    *(const s16x8*)&s_stage[(tn*16 + lm) * STR + kk*32 + q*8];
    }
}

__global__ __launch_bounds__(256, 3)
void narx_kernel(const float* __restrict__ x,
                 const float* __restrict__ Win,
                 const float* __restrict__ bin_g,
                 const unsigned short* __restrict__ wfrag,
                 const float* __restrict__ bh_g,
                 const float* __restrict__ Wout,
                 const float* __restrict__ bout_g,
                 float* __restrict__ out)
{
    __shared__ unsigned short s_win[HIDN * SW];     // resident Win^T + bin row

    const int tid   = threadIdx.x;
    const int lane  = tid & 63;
    const int lm    = lane & 15;
    const int q     = lane >> 4;
    const int G0    = blockIdx.x * GBLK;
    const int tt0   = blockIdx.y * TTB;
    const int wrow0 = (tid >> 6) * 16;
    const int myg   = G0 + wrow0 + lm;

    // zero the t<DLAG head of the output (poisoned before every launch)
    if (blockIdx.y == 0 && tid < GBLK) {
        #pragma unroll
        for (int t2 = 0; t2 < DLAG; ++t2)
            out[t2 * NG + G0 + tid] = 0.0f;
    }

    // ---- load prepacked Wxh/Whh fragments (coalesced dwordx4, L2-hit) ----
    s16x8 wxhf[4][2], whhf[4][2];
    #pragma unroll
    for (int tn = 0; tn < 4; ++tn)
        #pragma unroll
        for (int kk = 0; kk < 2; ++kk) {
            wxhf[tn][kk] = *(const s16x8*)&wfrag[WXH_OFF + lane*64 + tn*16 + kk*8];
            whhf[tn][kk] = *(const s16x8*)&wfrag[WHH_OFF + lane*64 + tn*16 + kk*8];
        }

    // ---- build s_win: slots k<16 = Win^T, slot 16 = bin, 17..31 = 0 ----
    {
        int r = tid >> 2, c0 = 16 + (tid & 3) * 4;
        #pragma unroll
        for (int i = 0; i < 4; ++i) {
            unsigned short v = 0;
            if (c0 + i == 16) v = f2bf(bin_g[r]);
            s_win[r * SW + c0 + i] = v;
        }
    }
    {
        int k = tid >> 4, nn = (tid & 15) * 4;
        const float* src = Win + k * HIDN + nn;
        #pragma unroll
        for (int i = 0; i < 4; ++i) s_win[(nn + i) * SW + k] = f2bf(src[i]);
    }

    // b_h (scaled) fp32 per-lane: unit n = tn*16 + q*4 + r
    f32x4 bhf4[4];
    #pragma unroll
    for (int tn = 0; tn < 4; ++tn) {
        f32x4 h4 = *(const f32x4*)&bh_g[tn*16 + q*4];
        bhf4[tn] = h4 * SCALE;
    }
    const float boutf = bout_g[0];
    __syncthreads();   // s_win fully written

    // ---- skewed hot loop over slices tt0 .. tt0+6 ----
    const size_t slcstride = (size_t)NG * NXF;
    const float* px = x + ((size_t)tt0 * NG + myg) * NXF + q * 8;

    // load + pack slice s into a ready B-frag (q==2 carries the bias 1.0)
    auto load_pack = [&](int s) -> s16x8 {
        s16x8 r = {0,0,0,0,0,0,0,0};
        if (q == 2) r[0] = (short)0x3F80;   // bf16(1.0) at k=16 -> +bin
        if (q < 2) {   // features k = q*8+j < 16
            const float* p = px + (size_t)s * slcstride;
            f32x4 a = *(const f32x4*)p;
            f32x4 b = *(const f32x4*)(p + 4);
            u32x4 xi;
            xi[0] = pk2bf(a[0], a[1]);
            xi[1] = pk2bf(a[2], a[3]);
            xi[2] = pk2bf(b[0], b[1]);
            xi[3] = pk2bf(b[2], b[3]);
            r = __builtin_bit_cast(s16x8, xi);
        }
        return r;
    };

    u32x4 hpk[TTB][2];   // packed h per output chain (= next step's B-frags)
    s16x8 xf = load_pack(0);

    #pragma unroll
    for (int s = 0; s < NSLC; ++s) {
        // prefetch+pack slice s+1 (independent; lands during this compute)
        s16x8 xf_nxt = xf;
        if (s + 1 < NSLC) xf_nxt = load_pack(s + 1);

        // ---- u(s) = relu(x_s @ Win + bin), computed once, packed bf16 ----
        u32x4 upk[2];
        #pragma unroll
        for (int tj = 0; tj < 4; ++tj) {
            s16x8 wf = *(const s16x8*)&s_win[(tj*16 + lm) * SW + q*8];
            f32x4 zc = {0.f, 0.f, 0.f, 0.f};
            f32x4 ua = __builtin_amdgcn_mfma_f32_16x16x32_bf16(wf, xf, zc, 0, 0, 0);
            upk[tj>>1][(tj&1)*2+0] = pk2bf(fmaxf(ua[0],0.f), fmaxf(ua[1],0.f));
            upk[tj>>1][(tj&1)*2+1] = pk2bf(fmaxf(ua[2],0.f), fmaxf(ua[3],0.f));
        }
        const s16x8 uf0 = __builtin_bit_cast(s16x8, upk[0]);
        const s16x8 uf1 = __builtin_bit_cast(s16x8, upk[1]);

        // ---- advance every active chain: ti in [s-3, s] (independent!) ----
        #pragma unroll
        for (int ti = 0; ti < TTB; ++ti) {
            if (ti > s || ti < s - (DLAG - 1)) continue;   // compile-time pruned

            f32x4 ha[4];
            #pragma unroll
            for (int tn = 0; tn < 4; ++tn)
                ha[tn] = __builtin_amdgcn_mfma_f32_16x16x32_bf16(
                    wxhf[tn][0], uf0, bhf4[tn], 0, 0, 0);
            #pragma unroll
            for (int tn = 0; tn < 4; ++tn)
                ha[tn] = __builtin_amdgcn_mfma_f32_16x16x32_bf16(
                    wxhf[tn][1], uf1, ha[tn], 0, 0, 0);

            if (ti != s) {   // d>0: previous h exists
                #pragma unroll
                for (int kk = 0; kk < 2; ++kk) {
                    s16x8 hf = __builtin_bit_cast(s16x8, hpk[ti][kk]);
                    #pragma unroll
                    for (int tn = 0; tn < 4; ++tn)
                        ha[tn] = __builtin_amdgcn_mfma_f32_16x16x32_bf16(
                            whhf[tn][kk], hf, ha[tn], 0, 0, 0);
                }
            }

            if (ti > s - (DLAG - 1)) {
                // not the last step of this chain: h = tanh(.), pack for reuse
                #pragma unroll
                for (int tn = 0; tn < 4; ++tn) {
                    hpk[ti][tn>>1][(tn&1)*2+0] =
                        pk2bf(tanh_pre(ha[tn][0]), tanh_pre(ha[tn][1]));
                    hpk[ti][tn>>1][(tn&1)*2+1] =
                        pk2bf(tanh_pre(ha[tn][2]), tanh_pre(ha[tn][3]));
                }
            } else {
                // last step (s == ti+3): y = Wout.h + bout
                float acc = 0.f;
                #pragma unroll
                for (int tn = 0; tn < 4; ++tn) {
                    f32x4 wo = *(const f32x4*)&Wout[tn*16 + q*4];
                    #pragma unroll
                    for (int r = 0; r < 4; ++r)
                        acc += tanh_pre(ha[tn][r]) * wo[r];
                }
                acc += __shfl_xor(acc, 16, 64);
                acc += __shfl_xor(acc, 32, 64);
                if (lane < 16)
                    out[(size_t)(tt0 + ti + DLAG) * NG + G0 + wrow0 + lane] =
                        acc + boutf;
            }
        }

        xf = xf_nxt;
    }
}

extern "C" void kernel_launch(void* const* d_in, const int* in_sizes, int n_in,
                              void* d_out, int out_size, void* d_ws, size_t ws_size,
                              hipStream_t stream) {
    const float* x    = (const float*)d_in[0];
    const float* Win  = (const float*)d_in[1];
    const float* bin  = (const float*)d_in[2];
    const float* Wxh  = (const float*)d_in[3];
    const float* Whh  = (const float*)d_in[4];
    const float* bh   = (const float*)d_in[5];
    const float* Wout = (const float*)d_in[6];
    const float* bout = (const float*)d_in[7];
    float* out = (float*)d_out;
    unsigned short* ws = (unsigned short*)d_ws;

    pack_weights<<<dim3(1), dim3(256), 0, stream>>>(Wxh, Whh, ws);

    dim3 grid(NG / GBLK, TOUTN / TTB);  // (32, 127)
    narx_kernel<<<grid, dim3(256), 0, stream>>>(x, Win, bin, ws, bh, Wout, bout, out);
}